// Round 1
// baseline (294.474 us; speedup 1.0000x reference)
//
#include <hip/hip_runtime.h>
#include <math.h>

// Problem constants (fixed by reference)
#define N_V  2048   // vertices
#define N_E  8192   // edges
#define HVC  256    // HV
#define MVC  256    // MV
#define MEC  256    // ME

// Workspace layout (float/int element offsets into d_ws, 4B units):
//   src    [0      , 8192 )
//   dst    [8192   , 16384)
//   indeg  [16384  , 18432)
//   sumAll [18432  , 18688)
//   X      [32768  , +2048*256)
//   Au     [557056 , +2048*256)
//   Av     [1081344, +2048*256)   -> total ~6.2 MB (well under typical ws)

static __device__ __forceinline__ float leaky(float x) {
    return x >= 0.f ? x : 0.01f * x;
}

// ---- K1: scan one-hot vew1/vew2 -> src/dst indices + in-degree counts ----
__global__ __launch_bounds__(256) void k_scan(const float4* __restrict__ vew1,
                                              const float4* __restrict__ vew2,
                                              int* __restrict__ src,
                                              int* __restrict__ dst,
                                              int* __restrict__ indeg)
{
    const int NE4 = N_V * (N_E / 4);
    const int total = 2 * NE4;
    const int stride = gridDim.x * blockDim.x;
    for (int idx = blockIdx.x * blockDim.x + threadIdx.x; idx < total; idx += stride) {
        const bool second = (idx >= NE4);
        const int i = second ? idx - NE4 : idx;
        const float4 v = second ? vew2[i] : vew1[i];
        if (v.x != 0.f || v.y != 0.f || v.z != 0.f || v.w != 0.f) {
            const int n  = i / (N_E / 4);
            const int e4 = (i % (N_E / 4)) * 4;
            int* arr = second ? dst : src;
            if (v.x != 0.f) { arr[e4 + 0] = n; atomicAdd(&indeg[n], 1); }
            if (v.y != 0.f) { arr[e4 + 1] = n; atomicAdd(&indeg[n], 1); }
            if (v.z != 0.f) { arr[e4 + 2] = n; atomicAdd(&indeg[n], 1); }
            if (v.w != 0.f) { arr[e4 + 3] = n; atomicAdd(&indeg[n], 1); }
        }
    }
}

// ---- K2: per-vertex GEMMs. blockIdx.y selects {X, Au, Av}. ----
// X  = leaky(hv @ attend_w + attend_b)
// Au = hv @ Wu - Zp - Zq            (Wu = link_w rows [0,256))
// Av = hv @ Wv + Zp + Zq + link_b   (Wv = link_w rows [262,518))
// Zp[n][j] = sum_t p_ftr[n][t] * link_w[256+t][j]; Zq with rows 259..261.
__global__ __launch_bounds__(256) void k_gemm(const float* __restrict__ hv,
                                              const float* __restrict__ attend_w,
                                              const float* __restrict__ attend_b,
                                              const float* __restrict__ link_w,
                                              const float* __restrict__ link_b,
                                              const float* __restrict__ p_ftr,
                                              const float* __restrict__ q_ftr,
                                              float* __restrict__ X,
                                              float* __restrict__ Au,
                                              float* __restrict__ Av)
{
    const int mat  = blockIdx.y;           // 0:X 1:Au 2:Av
    const int row0 = blockIdx.x * 16;
    const int j    = threadIdx.x;          // output column 0..255

    const float* B = (mat == 0) ? attend_w : (mat == 1 ? link_w : link_w + 262 * 256);

    float acc[16];
#pragma unroll
    for (int r = 0; r < 16; ++r) acc[r] = 0.f;

    const float* Abase = hv + row0 * HVC;
    for (int k = 0; k < 256; k += 4) {
        const float b0 = B[(k + 0) * 256 + j];
        const float b1 = B[(k + 1) * 256 + j];
        const float b2 = B[(k + 2) * 256 + j];
        const float b3 = B[(k + 3) * 256 + j];
#pragma unroll
        for (int r = 0; r < 16; ++r) {
            const float4 a = *reinterpret_cast<const float4*>(Abase + r * HVC + k);
            acc[r] = fmaf(a.x, b0, fmaf(a.y, b1, fmaf(a.z, b2, fmaf(a.w, b3, acc[r]))));
        }
    }

    if (mat == 0) {
        const float bias = attend_b[j];
#pragma unroll
        for (int r = 0; r < 16; ++r) {
            X[(row0 + r) * 256 + j] = leaky(acc[r] + bias);
        }
    } else {
        // p/q contribution rows of link_w (6 rows, L2-resident)
        const float wp0 = link_w[(256 + 0) * 256 + j];
        const float wp1 = link_w[(256 + 1) * 256 + j];
        const float wp2 = link_w[(256 + 2) * 256 + j];
        const float wq0 = link_w[(259 + 0) * 256 + j];
        const float wq1 = link_w[(259 + 1) * 256 + j];
        const float wq2 = link_w[(259 + 2) * 256 + j];
        const float lb = (mat == 2) ? link_b[j] : 0.f;
#pragma unroll
        for (int r = 0; r < 16; ++r) {
            const int row = row0 + r;
            float zpq = p_ftr[row * 3 + 0] * wp0 + p_ftr[row * 3 + 1] * wp1 +
                        p_ftr[row * 3 + 2] * wp2 + q_ftr[row * 3 + 0] * wq0 +
                        q_ftr[row * 3 + 1] * wq1 + q_ftr[row * 3 + 2] * wq2;
            if (mat == 1) Au[row * 256 + j] = acc[r] - zpq;
            else          Av[row * 256 + j] = acc[r] + zpq + lb;
        }
    }
}

// ---- K3: sumAll[j] = sum_m indeg[m] * X[m][j]  (fallback for indeg==0) ----
__global__ __launch_bounds__(256) void k_sumall(const float* __restrict__ X,
                                                const int* __restrict__ indeg,
                                                float* __restrict__ sumAll)
{
    const int j  = threadIdx.x;
    const int m0 = blockIdx.x * 128;
    float s = 0.f;
    for (int m = m0; m < m0 + 128; ++m) {
        const float d = (float)indeg[m];
        s = fmaf(d, X[m * 256 + j], s);
    }
    atomicAdd(&sumAll[j], s);
}

// ---- K4: mv_ftr[n] = elu(X[n]) if indeg>0 else elu(sumAll/2E) ----
__global__ __launch_bounds__(256) void k_mv(const float* __restrict__ X,
                                            const int* __restrict__ indeg,
                                            const float* __restrict__ sumAll,
                                            float* __restrict__ out)
{
    const int j  = threadIdx.x;
    const int n0 = blockIdx.x * 8;
#pragma unroll
    for (int r = 0; r < 8; ++r) {
        const int n = n0 + r;
        const float v = (indeg[n] > 0) ? X[n * 256 + j]
                                       : sumAll[j] * (1.0f / (2.0f * N_E));
        out[n * 256 + j] = (v > 0.f) ? v : expm1f(v);
    }
}

// ---- K5: me_ftr[e'] = leaky(Au[u[e']] + Av[v[e']]) ----
__global__ __launch_bounds__(256) void k_me(const int* __restrict__ src,
                                            const int* __restrict__ dst,
                                            const float* __restrict__ Au,
                                            const float* __restrict__ Av,
                                            float* __restrict__ out_me)
{
    const int t    = threadIdx.x;
    const int lane = t & 63;
    const int e    = blockIdx.x * 4 + (t >> 6);  // 4 edges per block, 1 wave each
    int u, v;
    if (e < N_E) { u = src[e]; v = dst[e]; }
    else         { u = dst[e - N_E]; v = src[e - N_E]; }
    const float4 a = *reinterpret_cast<const float4*>(&Au[u * 256 + lane * 4]);
    const float4 b = *reinterpret_cast<const float4*>(&Av[v * 256 + lane * 4]);
    float4 o;
    o.x = leaky(a.x + b.x);
    o.y = leaky(a.y + b.y);
    o.z = leaky(a.z + b.z);
    o.w = leaky(a.w + b.w);
    *reinterpret_cast<float4*>(&out_me[e * 256 + lane * 4]) = o;
}

extern "C" void kernel_launch(void* const* d_in, const int* in_sizes, int n_in,
                              void* d_out, int out_size, void* d_ws, size_t ws_size,
                              hipStream_t stream) {
    const float* hv       = (const float*)d_in[0];
    // d_in[1] he_ftr: unused (align path is dead code — softmax weights sum to 1)
    const float* p_ftr    = (const float*)d_in[2];
    const float* q_ftr    = (const float*)d_in[3];
    const float* vew1     = (const float*)d_in[4];
    const float* vew2     = (const float*)d_in[5];
    // d_in[6], d_in[7] veb1/veb2: redundant with vew
    const float* attend_w = (const float*)d_in[8];
    const float* attend_b = (const float*)d_in[9];
    // d_in[10], d_in[11] align_w/align_b: dead code
    const float* link_w   = (const float*)d_in[12];
    const float* link_b   = (const float*)d_in[13];

    float* out = (float*)d_out;
    float* ws  = (float*)d_ws;

    int*   src    = (int*)ws;
    int*   dst    = src + N_E;
    int*   indeg  = dst + N_E;
    float* sumAll = ws + 18432;
    float* X      = ws + 32768;
    float* Au     = X + N_V * 256;
    float* Av     = Au + N_V * 256;

    // zero the accumulators (ws is poisoned to 0xAA before every launch)
    hipMemsetAsync(indeg, 0, N_V * sizeof(int), stream);
    hipMemsetAsync(sumAll, 0, 256 * sizeof(float), stream);

    k_scan<<<8192, 256, 0, stream>>>((const float4*)vew1, (const float4*)vew2,
                                     src, dst, indeg);

    dim3 g2(N_V / 16, 3);
    k_gemm<<<g2, 256, 0, stream>>>(hv, attend_w, attend_b, link_w, link_b,
                                   p_ftr, q_ftr, X, Au, Av);

    k_sumall<<<16, 256, 0, stream>>>(X, indeg, sumAll);

    k_mv<<<N_V / 8, 256, 0, stream>>>(X, indeg, sumAll, out);

    k_me<<<(2 * N_E) / 4, 256, 0, stream>>>(src, dst, Au, Av, out + N_V * MVC);
}